// Round 3
// baseline (210.338 us; speedup 1.0000x reference)
//
#include <hip/hip_runtime.h>

#define NN   2048
#define IN   64
#define HID  32
#define OUTD 16
#define NB   64      // 64 blocks, 32 output rows each; 1 block/CU, no co-residency needed

// Single non-cooperative kernel. Each block is self-sufficient:
//   - streams all of x to get s0 = colsum(x)           (L2-resident, ~512 KB)
//   - agg1 = bias1 + coeff1[0,0] * (s0 @ bases1[0])
//   - sweeps all 64 row-tiles computing h1 = relu(x@W1 + agg1), accumulating
//     s1 = colsum(h1) (redundant across blocks), keeping its OWN tile in LDS
//   - agg2 = bias2 + s1 @ (sum_r coeff2[0,r] bases2[r])
//   - out rows = h1own @ loop_w2 + agg2
// No ws, no atomics, no grid sync, one graph node.

__global__ __launch_bounds__(256) void rgcn_mono(
    const float* __restrict__ x,
    const float* __restrict__ bases1,
    const float* __restrict__ coeff1,
    const float* __restrict__ loop_w1,
    const float* __restrict__ bias1,
    const float* __restrict__ bases2,
    const float* __restrict__ coeff2,
    const float* __restrict__ loop_w2,
    const float* __restrict__ bias2,
    float* __restrict__ out)
{
    __shared__ float w1sh[IN * HID];        // 8 KB
    __shared__ float xtile[32 * IN];        // 8 KB (also pass-1 reduce scratch)
    __shared__ float h1own[32 * (HID + 1)]; // own h1 tile, +1 pad
    __shared__ float w2sh[HID * OUTD];
    __shared__ float w2csh[HID * OUTD];
    __shared__ float s0sh[IN];
    __shared__ float agg1sh[HID];
    __shared__ float s1sh[HID];
    __shared__ float agg2sh[OUTD];
    __shared__ float scratch[256];

    const int tid = threadIdx.x;
    const int b   = blockIdx.x;

    // ---- stage weights ----------------------------------------------------
    for (int i = tid; i < IN * HID; i += 256) w1sh[i] = loop_w1[i];
    {
        const float c20 = coeff2[0], c21 = coeff2[1], c22 = coeff2[2], c23 = coeff2[3];
        for (int i = tid; i < HID * OUTD; i += 256) {
            w2sh[i]  = loop_w2[i];
            w2csh[i] = c20 * bases2[i]        + c21 * bases2[512 + i] +
                       c22 * bases2[1024 + i] + c23 * bases2[1536 + i];
        }
    }

    // ---- pass 1: s0 = colsum(x), float4 grid-stride (c4 = tid&15 fixed) ---
    {
        const float4* x4 = (const float4*)x;
        float4 a4 = make_float4(0.f, 0.f, 0.f, 0.f);
        for (int i = tid; i < NN * (IN / 4); i += 256) {
            float4 v = x4[i];
            a4.x += v.x; a4.y += v.y; a4.z += v.z; a4.w += v.w;
        }
        ((float4*)xtile)[tid] = a4;          // xtile as 4 KB reduce scratch
        __syncthreads();
        if (tid < IN) {                      // col = 4*c4+comp
            const int c4 = tid >> 2, comp = tid & 3;
            float s = 0.f;
#pragma unroll
            for (int g = 0; g < 16; ++g)
                s += xtile[(g * 16 + c4) * 4 + comp];
            s0sh[tid] = s;
        }
        __syncthreads();
    }

    // ---- agg1 -------------------------------------------------------------
    {
        const float c1 = coeff1[0];
        const int hh = tid & 31, seg = tid >> 5;
        float p = 0.f;
#pragma unroll
        for (int k = 0; k < 8; ++k)
            p += s0sh[seg * 8 + k] * bases1[(seg * 8 + k) * HID + hh];
        scratch[tid] = p;
        __syncthreads();
        if (tid < HID) {
            float s = 0.f;
#pragma unroll
            for (int g = 0; g < 8; ++g) s += scratch[g * 32 + tid];
            agg1sh[tid] = bias1[tid] + c1 * s;
        }
        __syncthreads();
    }

    // ---- pass 2: sweep all tiles; s1 colsum + capture own tile ------------
    const int h = tid & 31, rgrp = tid >> 5;      // thread: col h, rows rgrp+{0,8,16,24}
    float4 wq[16];                                 // w1 column h in registers
#pragma unroll
    for (int kq = 0; kq < 16; ++kq)
        wq[kq] = make_float4(w1sh[(4 * kq + 0) * HID + h], w1sh[(4 * kq + 1) * HID + h],
                             w1sh[(4 * kq + 2) * HID + h], w1sh[(4 * kq + 3) * HID + h]);
    const float agg1v = agg1sh[h];

    float s1acc = 0.f;
    for (int t = 0; t < NN / 32; ++t) {
        const float4* xt4 = (const float4*)(x + t * 32 * IN);
        ((float4*)xtile)[tid]       = xt4[tid];
        ((float4*)xtile)[tid + 256] = xt4[tid + 256];
        __syncthreads();

        const float4* r0 = (const float4*)(xtile + (rgrp +  0) * IN);
        const float4* r1 = (const float4*)(xtile + (rgrp +  8) * IN);
        const float4* r2 = (const float4*)(xtile + (rgrp + 16) * IN);
        const float4* r3 = (const float4*)(xtile + (rgrp + 24) * IN);
        // packed pairs to encourage v_pk_fma_f32
        float2 p0 = make_float2(0.f, 0.f), p1 = p0, p2 = p0, p3 = p0;
#pragma unroll
        for (int kq = 0; kq < 16; ++kq) {
            const float4 w = wq[kq];
            const float4 v0 = r0[kq], v1 = r1[kq], v2 = r2[kq], v3 = r3[kq];
            p0.x += v0.x * w.x; p0.y += v0.y * w.y; p0.x += v0.z * w.z; p0.y += v0.w * w.w;
            p1.x += v1.x * w.x; p1.y += v1.y * w.y; p1.x += v1.z * w.z; p1.y += v1.w * w.w;
            p2.x += v2.x * w.x; p2.y += v2.y * w.y; p2.x += v2.z * w.z; p2.y += v2.w * w.w;
            p3.x += v3.x * w.x; p3.y += v3.y * w.y; p3.x += v3.z * w.z; p3.y += v3.w * w.w;
        }
        float a0 = fmaxf(agg1v + p0.x + p0.y, 0.f);
        float a1 = fmaxf(agg1v + p1.x + p1.y, 0.f);
        float a2 = fmaxf(agg1v + p2.x + p2.y, 0.f);
        float a3 = fmaxf(agg1v + p3.x + p3.y, 0.f);
        s1acc += a0 + a1 + a2 + a3;
        if (t == b) {
            h1own[(rgrp +  0) * (HID + 1) + h] = a0;
            h1own[(rgrp +  8) * (HID + 1) + h] = a1;
            h1own[(rgrp + 16) * (HID + 1) + h] = a2;
            h1own[(rgrp + 24) * (HID + 1) + h] = a3;
        }
        __syncthreads();
    }

    // ---- s1 reduce, agg2 --------------------------------------------------
    scratch[tid] = s1acc;
    __syncthreads();
    if (tid < HID) {
        float s = 0.f;
#pragma unroll
        for (int g = 0; g < 8; ++g) s += scratch[g * 32 + tid];
        s1sh[tid] = s;
    }
    __syncthreads();
    if (tid < OUTD) {
        float s = 0.f;
#pragma unroll
        for (int hh = 0; hh < HID; ++hh) s += s1sh[hh] * w2csh[hh * OUTD + tid];
        agg2sh[tid] = bias2[tid] + s;
    }
    __syncthreads();

    // ---- out: own 32 rows x 16 cols, coalesced ----------------------------
    for (int idx = tid; idx < 32 * OUTD; idx += 256) {
        const int row = idx >> 4, o = idx & 15;
        float acc = agg2sh[o];
#pragma unroll
        for (int hh = 0; hh < HID; ++hh)
            acc += h1own[row * (HID + 1) + hh] * w2sh[hh * OUTD + o];
        out[b * 32 * OUTD + idx] = acc;
    }
}

extern "C" void kernel_launch(void* const* d_in, const int* in_sizes, int n_in,
                              void* d_out, int out_size, void* d_ws, size_t ws_size,
                              hipStream_t stream) {
    const float* x       = (const float*)d_in[0];
    // d_in[1] = adj_matrix: mathematically unused (complete graph w/ self-loops)
    const float* bases1  = (const float*)d_in[2];
    const float* coeff1  = (const float*)d_in[3];
    const float* loop_w1 = (const float*)d_in[4];
    const float* bias1   = (const float*)d_in[5];
    const float* bases2  = (const float*)d_in[6];
    const float* coeff2  = (const float*)d_in[7];
    const float* loop_w2 = (const float*)d_in[8];
    const float* bias2   = (const float*)d_in[9];
    float* out = (float*)d_out;

    rgcn_mono<<<NB, 256, 0, stream>>>(x, bases1, coeff1, loop_w1, bias1,
                                      bases2, coeff2, loop_w2, bias2, out);
}

// Round 4
// 89.256 us; speedup vs baseline: 2.3566x; 2.3566x over previous
//
#include <hip/hip_runtime.h>

#define NN   2048
#define IN   64
#define HID  32
#define OUTD 16

// Dataflow: s0=colsum(x) -> agg1 -> h1=relu(x@W1+agg1) -> s1=colsum(h1)
//           -> agg2 -> out = h1@W2 + agg2
// Two global reductions => 3 kernels minimum (grid.sync measured slower, R1;
// per-block redundant h1 measured much slower, R2).
//
// ws layout (floats) — every slot is write-before-read (0xAA poison harmless):
//   [S0P, S0P+64*64)   : K1 per-block partial colsums of x   (64 blocks x 64)
//   [H1O, H1O+2048*32) : h1, row-major                       (written by K2)
//   [S1P, S1P+64*32)   : K2 per-block partial colsums of h1  (64 blocks x 32)
#define S0P 0
#define H1O 4096
#define S1P (4096 + NN * HID)

// ---------------------------------------------------------------- K1 -------
__global__ __launch_bounds__(256) void k1_colsum_x(const float* __restrict__ x,
                                                   float* __restrict__ ws) {
    __shared__ float red[256];
    const int tid = threadIdx.x, b = blockIdx.x;   // 64 blocks x 32 rows
    const int col = tid & 63, grp = tid >> 6;      // 4 groups x 8 rows
    const float* xb = x + b * 32 * IN;
    float s = 0.f;
#pragma unroll
    for (int r = 0; r < 8; ++r)                    // 8 independent coalesced loads
        s += xb[(grp * 8 + r) * IN + col];
    red[tid] = s;
    __syncthreads();
    if (tid < 64)
        ws[S0P + b * 64 + tid] = red[tid] + red[tid + 64] + red[tid + 128] + red[tid + 192];
}

// ---------------------------------------------------------------- K2 -------
__global__ __launch_bounds__(256) void k2_layer1(const float* __restrict__ x,
                                                 const float* __restrict__ bases1,
                                                 const float* __restrict__ coeff1,
                                                 const float* __restrict__ loop_w1,
                                                 const float* __restrict__ bias1,
                                                 float* __restrict__ ws) {
    __shared__ float w1sh[IN * HID];   // 8 KB
    __shared__ float xsh[32 * IN];     // 8 KB
    __shared__ float s0sh[IN];
    __shared__ float agg1sh[HID];
    __shared__ float red[256];
    const int tid = threadIdx.x, b = blockIdx.x;   // 64 blocks x 32 rows

    // stage own x tile + w1 (float4, 2/thread each, all independent)
    const float4* x4  = (const float4*)(x + b * 32 * IN);
    const float4* w14 = (const float4*)loop_w1;
    float4 xa = x4[tid], xb4 = x4[tid + 256];
    float4 wa = w14[tid], wb = w14[tid + 256];

    // reduce s0 partials (64 x 64) — 16 independent L2 loads per thread
    {
        const int col = tid & 63, g = tid >> 6;    // g sums blocks 16g..16g+15
        float a0 = 0.f, a1 = 0.f, a2 = 0.f, a3 = 0.f;
#pragma unroll
        for (int k = 0; k < 4; ++k) {
            a0 += ws[S0P + (g * 16 + k     ) * 64 + col];
            a1 += ws[S0P + (g * 16 + 4 + k ) * 64 + col];
            a2 += ws[S0P + (g * 16 + 8 + k ) * 64 + col];
            a3 += ws[S0P + (g * 16 + 12 + k) * 64 + col];
        }
        ((float4*)xsh)[tid] = xa; ((float4*)xsh)[tid + 256] = xb4;
        ((float4*)w1sh)[tid] = wa; ((float4*)w1sh)[tid + 256] = wb;
        red[tid] = a0 + a1 + a2 + a3;
    }
    __syncthreads();
    if (tid < 64)
        s0sh[tid] = red[tid] + red[tid + 64] + red[tid + 128] + red[tid + 192];
    __syncthreads();

    // agg1[h] = bias1[h] + c1 * sum_k s0[k]*bases1[k*HID+h]
    {
        const int h = tid & 31, seg = tid >> 5;
        float p = 0.f;
#pragma unroll
        for (int k = 0; k < 8; ++k)
            p += s0sh[seg * 8 + k] * bases1[(seg * 8 + k) * HID + h];
        red[tid] = p;
        __syncthreads();
        if (tid < HID) {
            float t = 0.f;
#pragma unroll
            for (int g = 0; g < 8; ++g) t += red[g * 32 + tid];
            agg1sh[tid] = bias1[tid] + coeff1[0] * t;
        }
    }
    __syncthreads();

    // h1 for 32 rows: thread = (h = tid&31, rgrp = tid>>5), rows rgrp + {0,8,16,24}
    {
        const int h = tid & 31, rgrp = tid >> 5;
        const float agg1v = agg1sh[h];
        float a0 = agg1v, a1 = agg1v, a2 = agg1v, a3 = agg1v;
#pragma unroll
        for (int k = 0; k < IN; ++k) {
            const float w = w1sh[k * HID + h];     // broadcast within wave
            a0 += xsh[(rgrp +  0) * IN + k] * w;
            a1 += xsh[(rgrp +  8) * IN + k] * w;
            a2 += xsh[(rgrp + 16) * IN + k] * w;
            a3 += xsh[(rgrp + 24) * IN + k] * w;
        }
        a0 = fmaxf(a0, 0.f); a1 = fmaxf(a1, 0.f);
        a2 = fmaxf(a2, 0.f); a3 = fmaxf(a3, 0.f);
        // h1 store: per wave, rows {rgrp, rgrp+1} x h0-31 => 256B coalesced
        float* h1b = ws + H1O + b * 32 * HID;
        h1b[(rgrp +  0) * HID + h] = a0;
        h1b[(rgrp +  8) * HID + h] = a1;
        h1b[(rgrp + 16) * HID + h] = a2;
        h1b[(rgrp + 24) * HID + h] = a3;
        red[tid] = a0 + a1 + a2 + a3;              // partial s1
    }
    __syncthreads();
    if (tid < HID) {
        float t = 0.f;
#pragma unroll
        for (int g = 0; g < 8; ++g) t += red[g * 32 + tid];
        ws[S1P + b * HID + tid] = t;
    }
}

// ---------------------------------------------------------------- K3 -------
__global__ __launch_bounds__(256) void k3_layer2(const float* __restrict__ bases2,
                                                 const float* __restrict__ coeff2,
                                                 const float* __restrict__ loop_w2,
                                                 const float* __restrict__ bias2,
                                                 const float* __restrict__ ws,
                                                 float* __restrict__ out) {
    __shared__ float w2sh[HID * OUTD];     // loop_w2
    __shared__ float w2csh[HID * OUTD];    // sum_r coeff2[0,r]*bases2[r]
    __shared__ float h1sh[16 * (HID + 1)]; // own 16 rows, +1 pad
    __shared__ float s1sh[HID];
    __shared__ float agg2sh[OUTD];
    __shared__ float red[256];
    const int tid = threadIdx.x, b = blockIdx.x;   // 128 blocks x 16 rows

    // stage weights + combined basis (2 elements/thread)
    {
        const float c20 = coeff2[0], c21 = coeff2[1], c22 = coeff2[2], c23 = coeff2[3];
#pragma unroll
        for (int j = 0; j < 2; ++j) {
            const int i = tid + j * 256;
            w2sh[i]  = loop_w2[i];
            w2csh[i] = c20 * bases2[i]        + c21 * bases2[512 + i] +
                       c22 * bases2[1024 + i] + c23 * bases2[1536 + i];
        }
    }
    // own h1 tile: 512 floats, coalesced read, padded LDS write
    for (int j = 0; j < 2; ++j) {
        const int i = tid + j * 256;
        h1sh[(i >> 5) * (HID + 1) + (i & 31)] = ws[H1O + b * 16 * HID + i];
    }
    // reduce s1 partials (64 x 32): thread (h=tid&31, g=tid>>5) sums 8 blocks
    {
        const int h = tid & 31, g = tid >> 5;
        float a0 = 0.f, a1 = 0.f;
#pragma unroll
        for (int k = 0; k < 4; ++k) {
            a0 += ws[S1P + (g * 8 + k    ) * HID + h];
            a1 += ws[S1P + (g * 8 + 4 + k) * HID + h];
        }
        red[tid] = a0 + a1;
    }
    __syncthreads();
    if (tid < HID) {
        float t = 0.f;
#pragma unroll
        for (int g = 0; g < 8; ++g) t += red[g * 32 + tid];
        s1sh[tid] = t;
    }
    __syncthreads();
    if (tid < OUTD) {
        float s = 0.f;
#pragma unroll
        for (int h = 0; h < HID; ++h) s += s1sh[h] * w2csh[h * OUTD + tid];
        agg2sh[tid] = bias2[tid] + s;
    }
    __syncthreads();

    // out: 16 rows x 16 cols = 256 -> 1/thread, coalesced store
    {
        const int row = tid >> 4, o = tid & 15;
        float acc = agg2sh[o];
#pragma unroll
        for (int h = 0; h < HID; ++h)
            acc += h1sh[row * (HID + 1) + h] * w2sh[h * OUTD + o];
        out[b * 256 + tid] = acc;
    }
}

extern "C" void kernel_launch(void* const* d_in, const int* in_sizes, int n_in,
                              void* d_out, int out_size, void* d_ws, size_t ws_size,
                              hipStream_t stream) {
    const float* x       = (const float*)d_in[0];
    // d_in[1] = adj_matrix: mathematically unused (complete graph w/ self-loops)
    const float* bases1  = (const float*)d_in[2];
    const float* coeff1  = (const float*)d_in[3];
    const float* loop_w1 = (const float*)d_in[4];
    const float* bias1   = (const float*)d_in[5];
    const float* bases2  = (const float*)d_in[6];
    const float* coeff2  = (const float*)d_in[7];
    const float* loop_w2 = (const float*)d_in[8];
    const float* bias2   = (const float*)d_in[9];
    float* out = (float*)d_out;
    float* ws  = (float*)d_ws;

    k1_colsum_x<<<64, 256, 0, stream>>>(x, ws);
    k2_layer1 <<<64, 256, 0, stream>>>(x, bases1, coeff1, loop_w1, bias1, ws);
    k3_layer2 <<<128, 256, 0, stream>>>(bases2, coeff2, loop_w2, bias2, ws, out);
}